// Round 7
// baseline (474.995 us; speedup 1.0000x reference)
//
#include <hip/hip_runtime.h>
#include <hip/hip_bf16.h>
#include <math.h>

#define TOK   4096
#define DIM   1024
#define DMLP  4096
#define NE    8
#define BM    128
#define BN    128
#define BN2   64
#define BK    128
#define PADMAX (TOK + NE * BM)   // 5120 padded slots
#define NTILES (PADMAX / BM)     // 40 row-tiles
#define MAXSUP 24                // max 256-row supertiles: (40+8)/2

typedef __attribute__((ext_vector_type(8))) short  short8;
typedef __attribute__((ext_vector_type(4))) float  float4v;
typedef __attribute__((ext_vector_type(4))) unsigned short ushort4v;
typedef __attribute__((ext_vector_type(2))) unsigned long long ull2;

// async global->LDS, 16 B per lane; LDS dest is wave-uniform base + lane*16
#define ASYNC16(gp, lp) __builtin_amdgcn_global_load_lds( \
    (const __attribute__((address_space(1))) unsigned int*)(gp), \
    (__attribute__((address_space(3))) unsigned int*)(lp), 16, 0, 0)

// BK=128: 16 granules (8 bf16 = 16 B each) per row. Involution on low 3 bits.
#define SWZ(R, C) (((C) & 8) | (((C) ^ (R)) & 7))
// LDS granule offset (in shorts) for row R, k-granule C
#define FRAG_OFF(R, C) ((((R) << 4) + SWZ(R, C)) << 3)

static __device__ __forceinline__ unsigned short f2bf(float f) {
  unsigned u = __float_as_uint(f);
  u += 0x7fffu + ((u >> 16) & 1u);
  return (unsigned short)(u >> 16);
}

// exact-erf GELU via Abramowitz&Stegun 7.1.26 (|err| < 1.5e-7)
static __device__ __forceinline__ float gelu_erf(float v) {
  const float x = fabsf(v) * 0.70710678118654752f;
  const float t = __builtin_amdgcn_rcpf(1.0f + 0.3275911f * x);
  const float poly = ((((1.061405429f * t - 1.453152027f) * t + 1.421413741f) * t
                       - 0.284496736f) * t + 0.254829592f) * t;
  const float erf_abs = 1.0f - poly * __expf(-x * x);
  return 0.5f * v * (1.0f + copysignf(erf_abs, v));
}

// ---------------------------------------------------------------------------
// Kernel 1: group tokens by expert (single block). Emits 128-tile map AND
// 256-row supertile descriptors (two same-expert 128-tiles; odd leftover
// pairs with itself -> both halves compute identical values, benign).
// ---------------------------------------------------------------------------
__global__ void group_kernel(const int* __restrict__ eidx,
                             int* __restrict__ perm,
                             int* __restrict__ tile_e,
                             int* __restrict__ supA,
                             int* __restrict__ supB,
                             int* __restrict__ supE) {
  __shared__ int cnt[NE], off[NE], len[NE], cur[NE];
  const int tid = threadIdx.x;
  if (tid < NE) cnt[tid] = 0;
  __syncthreads();
  for (int i = tid; i < TOK; i += 256) atomicAdd(&cnt[eidx[i]], 1);
  __syncthreads();
  if (tid == 0) {
    int o = 0;
    for (int e = 0; e < NE; e++) {
      off[e] = o;
      len[e] = ((cnt[e] + BM - 1) / BM) * BM;
      cur[e] = o;
      o += len[e];
    }
    // build supertiles
    int ns = 0;
    for (int e = 0; e < NE; e++) {
      const int nt = len[e] / BM;
      for (int p = 0; p < nt; p += 2) {
        const int pb = (p + 1 < nt) ? (p + 1) : p;
        supA[ns] = off[e] + p * BM;
        supB[ns] = off[e] + pb * BM;
        supE[ns] = e;
        ns++;
      }
    }
    for (; ns < MAXSUP; ns++) { supA[ns] = 0; supB[ns] = 0; supE[ns] = -1; }
  }
  __syncthreads();
  for (int s = tid; s < PADMAX; s += 256) perm[s] = -1;
  __syncthreads();
  for (int i = tid; i < TOK; i += 256) {
    const int e = eidx[i];
    const int p = atomicAdd(&cur[e], 1);
    perm[p] = i;
  }
  __syncthreads();
  for (int t = tid; t < NTILES; t += 256) {
    const int row = t * BM;
    int te = -1;
    for (int e = 0; e < NE; e++)
      if (row >= off[e] && row < off[e] + len[e]) te = e;
    tile_e[t] = te;
  }
}

// ---------------------------------------------------------------------------
// conv body (v5, proven): W [E][K][N] f32 -> WT [E][N][K] bf16 per 64x64 tile
// ---------------------------------------------------------------------------
static __device__ __forceinline__
void conv_body(const float* __restrict__ W, unsigned short* __restrict__ WT,
               int K, int N, int bx, int by, int e, int tid,
               unsigned short T[64][68]) {
  const int k0 = by * 64, n0 = bx * 64;
  const float* Win = W + (size_t)e * K * N;
  unsigned short* Wout = WT + (size_t)e * K * N;
  const int i4 = tid & 15;          // n-quad: n = i4*4 + q
  const int kq = (tid >> 4) * 4;    // k base: 4 consecutive k
  float4v v[4];
#pragma unroll
  for (int j = 0; j < 4; j++)
    v[j] = *(const float4v*)(Win + (size_t)(k0 + kq + j) * N + n0 + i4 * 4);
#pragma unroll
  for (int q = 0; q < 4; q++) {
    ushort4v w;
#pragma unroll
    for (int j = 0; j < 4; j++) w[j] = f2bf(v[j][q]);
    *(ushort4v*)&T[i4 * 4 + q][kq] = w;
  }
  __syncthreads();
  const int g  = tid & 7;    // k-granule (8 shorts = 16 B)
  const int nb = tid >> 3;   // 0..31
#pragma unroll
  for (int r = 0; r < 2; r++) {
    const int n = nb + 32 * r;
    const unsigned long long v0 = *(const unsigned long long*)&T[n][g * 8];
    const unsigned long long v1 = *(const unsigned long long*)&T[n][g * 8 + 4];
    ull2 o; o[0] = v0; o[1] = v1;
    *(ull2*)&Wout[(size_t)(n0 + n) * K + k0 + g * 8] = o;
  }
}

// ---------------------------------------------------------------------------
// Kernel 2 (merged prep): conv(W1) + conv(W2) + xgather in ONE launch.
// Blocks [0,8192): W1 tiles; [8192,16384): W2 tiles; [16384,21504): xgather.
// Independent workloads fill each other's tails; 2 fewer launches.
// ---------------------------------------------------------------------------
__global__ __launch_bounds__(256)
void prep_kernel(const float* __restrict__ W1, unsigned short* __restrict__ W1T,
                 const float* __restrict__ W2, unsigned short* __restrict__ W2T,
                 const float* __restrict__ x, const int* __restrict__ perm,
                 unsigned short* __restrict__ xg) {
  __shared__ unsigned short T[64][68];
  const int bid = blockIdx.x;
  const int tid = threadIdx.x;
  if (bid < 8192) {
    // W1: grid (64,16,8): x=bid&63, y=(bid>>6)&15, z=bid>>10
    conv_body(W1, W1T, DIM, DMLP, bid & 63, (bid >> 6) & 15, bid >> 10, tid, T);
  } else if (bid < 16384) {
    const int b = bid - 8192;
    // W2: grid (16,64,8): x=b&15, y=(b>>4)&63, z=b>>10
    conv_body(W2, W2T, DMLP, DIM, b & 15, (b >> 4) & 63, b >> 10, tid, T);
  } else {
    const int slot = bid - 16384;
    const int t    = perm[slot];
    ushort4v o = (ushort4v){0, 0, 0, 0};
    if (t >= 0) {
      const float4v v = *(const float4v*)(x + (size_t)t * DIM + tid * 4);
#pragma unroll
      for (int q = 0; q < 4; q++) o[q] = f2bf(v[q]);
    }
    *(ushort4v*)(xg + (size_t)slot * DIM + tid * 4) = o;
  }
}

// ---------------------------------------------------------------------------
// Kernel 3: h = gelu(xg @ W1T^T + b1) -> bf16. 128x128 tile, BK=128
// (unchanged from round 6). Grid: (DMLP/BN, NTILES) col-fastest.
// ---------------------------------------------------------------------------
__global__ __launch_bounds__(256)
void gemm1_kernel(const unsigned short* __restrict__ xg,
                  const unsigned short* __restrict__ W1T,
                  const float* __restrict__ b1, const int* __restrict__ tile_e,
                  unsigned short* __restrict__ h) {
  const int bt = blockIdx.y;                 // row tile
  const int te = tile_e[bt];
  if (te < 0) return;
  const int n0 = blockIdx.x * BN;            // col tile
  const unsigned short* Asrc = xg + (size_t)bt * BM * DIM;
  const unsigned short* Bsrc = W1T + (size_t)te * DIM * DMLP + (size_t)n0 * DIM;
  const int tid = threadIdx.x;

  __shared__ __align__(16) unsigned short SMEM[2 * BM * BK];

  const int rr = tid >> 4, q = tid & 15;
  const int cs = SWZ(rr, q);
  const unsigned short* a0 = Asrc + (size_t)rr * DIM + cs * 8;
  const unsigned short* b0 = Bsrc + (size_t)rr * DIM + cs * 8;

  const int wid = tid >> 6, lane = tid & 63;
  const int wm = (wid >> 1) * 64, wn = (wid & 1) * 64;
  const int l15 = lane & 15, quad = lane >> 4;

  float4v acc[4][4];
#pragma unroll
  for (int i = 0; i < 4; i++)
#pragma unroll
    for (int j = 0; j < 4; j++) acc[i][j] = (float4v){0.f, 0.f, 0.f, 0.f};

  for (int k0 = 0; k0 < DIM; k0 += BK) {
#pragma unroll
    for (int t = 0; t < 8; t++)
      ASYNC16(a0 + (size_t)(16 * t) * DIM + k0, &SMEM[(t * 256 + tid) * 8]);
#pragma unroll
    for (int t = 0; t < 8; t++)
      ASYNC16(b0 + (size_t)(16 * t) * DIM + k0, &SMEM[BM * BK + (t * 256 + tid) * 8]);
    __syncthreads();

#pragma unroll
    for (int hh = 0; hh < 4; hh++) {
      short8 a[4], b[4];
      const int C = hh * 4 + quad;
#pragma unroll
      for (int i = 0; i < 4; i++)
        a[i] = *(const short8*)&SMEM[FRAG_OFF(wm + i * 16 + l15, C)];
#pragma unroll
      for (int j = 0; j < 4; j++)
        b[j] = *(const short8*)&SMEM[BM * BK + FRAG_OFF(wn + j * 16 + l15, C)];
#pragma unroll
      for (int i = 0; i < 4; i++)
#pragma unroll
        for (int j = 0; j < 4; j++)
          acc[i][j] = __builtin_amdgcn_mfma_f32_16x16x32_bf16(a[i], b[j], acc[i][j], 0, 0, 0);
    }
    __syncthreads();
  }

  // ---- epilogue: gelu -> bf16 into LDS tile, then coalesced wide stores ----
#pragma unroll
  for (int i = 0; i < 4; i++) {
#pragma unroll
    for (int j = 0; j < 4; j++) {
      const int colL = wn + j * 16 + l15;
      const float bias = b1[te * DMLP + n0 + colL];
#pragma unroll
      for (int r = 0; r < 4; r++) {
        const int rowL = wm + i * 16 + quad * 4 + r;
        SMEM[rowL * BN + colL] = f2bf(gelu_erf(acc[i][j][r] + bias));
      }
    }
  }
  __syncthreads();
  const int gg = tid & 15;       // 16-B granule within row
  const int rb = tid >> 4;       // row base 0..15
#pragma unroll
  for (int p = 0; p < 8; p++) {
    const int rowL = rb + p * 16;
    const ull2 v = *(const ull2*)&SMEM[rowL * BN + gg * 8];
    *(ull2*)&h[(size_t)(bt * BM + rowL) * DMLP + n0 + gg * 8] = v;
  }
}

// ---------------------------------------------------------------------------
// Kernel 4: out[tok] = h @ W2T^T + b2, scatter. 256x64 SUPERTILE, BK=128:
// 64 MFMA per wave per K-step (2x round-6) against the same drain count.
// A rows 0-127 from slot-base supA[s], 128-255 from supB[s] (same expert).
// LDS 80 KB -> 2 blocks/CU. Grid: (DIM/64, MAXSUP).
// ---------------------------------------------------------------------------
__global__ __launch_bounds__(256)
void gemm2_kernel(const unsigned short* __restrict__ h,
                  const unsigned short* __restrict__ W2T,
                  const float* __restrict__ b2, const int* __restrict__ perm,
                  const int* __restrict__ supA, const int* __restrict__ supB,
                  const int* __restrict__ supE, float* __restrict__ out) {
  const int s  = blockIdx.y;
  const int te = supE[s];
  if (te < 0) return;
  const int rowA = supA[s], rowB = supB[s];
  const int n0 = blockIdx.x * BN2;
  const int tid = threadIdx.x;

  __shared__ __align__(16) unsigned short As[256 * BK];   // 64 KB
  __shared__ __align__(16) unsigned short Bs[BN2 * BK];   // 16 KB

  const int rr = tid >> 4, q = tid & 15;
  const int cs = SWZ(rr, q);
  const unsigned short* aA = h + (size_t)(rowA + rr) * DMLP + cs * 8;
  const unsigned short* aB = h + (size_t)(rowB + rr) * DMLP + cs * 8;
  const unsigned short* b0 = W2T + (size_t)te * DMLP * DIM
                           + (size_t)(n0 + rr) * DMLP + cs * 8;

  const int wid = tid >> 6, lane = tid & 63;
  const int wm = wid * 64;                 // 0,64,128,192: 64 rows per wave
  const int l15 = lane & 15, quad = lane >> 4;

  float4v acc[4][4];
#pragma unroll
  for (int i = 0; i < 4; i++)
#pragma unroll
    for (int j = 0; j < 4; j++) acc[i][j] = (float4v){0.f, 0.f, 0.f, 0.f};

  for (int k0 = 0; k0 < DMLP; k0 += BK) {
#pragma unroll
    for (int t = 0; t < 8; t++)
      ASYNC16(aA + (size_t)(16 * t) * DMLP + k0, &As[(t * 256 + tid) * 8]);
#pragma unroll
    for (int t = 0; t < 8; t++)
      ASYNC16(aB + (size_t)(16 * t) * DMLP + k0, &As[((t + 8) * 256 + tid) * 8]);
#pragma unroll
    for (int t = 0; t < 4; t++)
      ASYNC16(b0 + (size_t)(16 * t) * DMLP + k0, &Bs[(t * 256 + tid) * 8]);
    __syncthreads();

#pragma unroll
    for (int hh = 0; hh < 4; hh++) {
      short8 a[4], b[4];
      const int C = hh * 4 + quad;
#pragma unroll
      for (int i = 0; i < 4; i++)
        a[i] = *(const short8*)&As[FRAG_OFF(wm + i * 16 + l15, C)];
#pragma unroll
      for (int j = 0; j < 4; j++)
        b[j] = *(const short8*)&Bs[FRAG_OFF(j * 16 + l15, C)];
#pragma unroll
      for (int i = 0; i < 4; i++)
#pragma unroll
        for (int j = 0; j < 4; j++)
          acc[i][j] = __builtin_amdgcn_mfma_f32_16x16x32_bf16(a[i], b[j], acc[i][j], 0, 0, 0);
    }
    __syncthreads();
  }

  const int halfbase = (wm < 128) ? (rowA + wm) : (rowB + (wm - 128));
#pragma unroll
  for (int i = 0; i < 4; i++) {
#pragma unroll
    for (int j = 0; j < 4; j++) {
      const int col = n0 + j * 16 + l15;
      const float bias = b2[te * DIM + col];
#pragma unroll
      for (int r = 0; r < 4; r++) {
        const int slot = halfbase + i * 16 + quad * 4 + r;
        const int t    = perm[slot];
        if (t >= 0) out[(size_t)t * DIM + col] = acc[i][j][r] + bias;
      }
    }
  }
}

// ---------------------------------------------------------------------------
extern "C" void kernel_launch(void* const* d_in, const int* in_sizes, int n_in,
                              void* d_out, int out_size, void* d_ws, size_t ws_size,
                              hipStream_t stream) {
  const float* x    = (const float*)d_in[0];
  const int*   eidx = (const int*)d_in[1];
  const float* W1   = (const float*)d_in[2];
  const float* b1   = (const float*)d_in[3];
  const float* W2   = (const float*)d_in[4];
  const float* b2   = (const float*)d_in[5];
  float* out = (float*)d_out;

  char* ws = (char*)d_ws;
  int* perm   = (int*)ws;                              // 5120 ints
  int* tile_e = (int*)(ws + PADMAX * sizeof(int));     // 40 ints @ 20480
  int* supA   = (int*)(ws + 20736);                    // 24 ints
  int* supB   = (int*)(ws + 20832);                    // 24 ints
  int* supE   = (int*)(ws + 20928);                    // 24 ints
  unsigned short* xg  = (unsigned short*)(ws + 32768);                      // 10 MB
  unsigned short* h   = (unsigned short*)(ws + 32768 + 10485760);           // 40 MB
  unsigned short* W1T = (unsigned short*)(ws + 32768 + 10485760 + 41943040);// 64 MB
  unsigned short* W2T = (unsigned short*)((char*)W1T + 67108864);           // 64 MB

  group_kernel<<<1, 256, 0, stream>>>(eidx, perm, tile_e, supA, supB, supE);
  prep_kernel<<<16384 + PADMAX, 256, 0, stream>>>(W1, W1T, W2, W2T, x, perm, xg);
  gemm1_kernel<<<dim3(DMLP / BN, NTILES), 256, 0, stream>>>(xg, W1T, b1, tile_e, h);
  gemm2_kernel<<<dim3(DIM / BN2, MAXSUP), 256, 0, stream>>>(h, W2T, b2, perm, supA, supB, supE, out);
}